// Round 2
// baseline (1181.212 us; speedup 1.0000x reference)
//
#include <hip/hip_runtime.h>
#include <cstdint>

#define NB 32
#define NN 1000
#define NC 1601
#define HID 64
#define ROWS (NB*NN)       // 32000
#define CAPB 15360         // candidate cap per batch
#define SROWS 15           // sample rows for threshold floor
#define NBIN 4096          // 12-bit key-prefix histogram

__device__ __forceinline__ uint32_t f2key(float f){
  uint32_t u = __float_as_uint(f);
  return (u & 0x80000000u) ? ~u : (u | 0x80000000u);   // monotone float->uint
}
__device__ __forceinline__ float key2f(uint32_t k){
  uint32_t u = (k & 0x80000000u) ? (k & 0x7fffffffu) : ~k;
  return __uint_as_float(u);
}

// ---------------------------------------------------------------------------
// Kernel A: fused 2-layer MLP for both heads. 64 rows/block, lane = row,
// 4 waves split K=1601. Cross-wave LDS reduce, bias+ReLU, 64x64 second GEMM.
// ---------------------------------------------------------------------------
__global__ __launch_bounds__(256, 2) void mlp_kernel(
    const float* __restrict__ x,
    const float* __restrict__ Ws1, const float* __restrict__ bs1,
    const float* __restrict__ Ws2, const float* __restrict__ bs2,
    const float* __restrict__ Wo1, const float* __restrict__ bo1,
    const float* __restrict__ Wo2, const float* __restrict__ bo2,
    float* __restrict__ subj, float* __restrict__ obj)
{
  __shared__ float red0[64*128];   // 32 KB
  __shared__ float red1[64*128];   // 32 KB
  const int tid  = threadIdx.x;
  const int lane = tid & 63;
  const int wave = tid >> 6;
  const int row  = blockIdx.x*64 + lane;
  const int kstart = (wave==0) ? 0   : 401 + (wave-1)*400;
  const int kend   = (wave==0) ? 401 : (kstart + 400);

  float accS[64], accO[64];
  #pragma unroll
  for (int j=0;j<64;j++){ accS[j]=0.f; accO[j]=0.f; }

  const float* xr = x + (size_t)row*NC;
  #pragma unroll 2
  for (int k=kstart; k<kend; k++){
    float xv = xr[k];
    int ku = __builtin_amdgcn_readfirstlane(k);
    const float4* wsp = (const float4*)(Ws1 + (size_t)ku*HID);
    const float4* wop = (const float4*)(Wo1 + (size_t)ku*HID);
    #pragma unroll
    for (int q=0;q<16;q++){
      float4 w = wsp[q];
      accS[4*q+0] = fmaf(xv, w.x, accS[4*q+0]);
      accS[4*q+1] = fmaf(xv, w.y, accS[4*q+1]);
      accS[4*q+2] = fmaf(xv, w.z, accS[4*q+2]);
      accS[4*q+3] = fmaf(xv, w.w, accS[4*q+3]);
    }
    #pragma unroll
    for (int q=0;q<16;q++){
      float4 w = wop[q];
      accO[4*q+0] = fmaf(xv, w.x, accO[4*q+0]);
      accO[4*q+1] = fmaf(xv, w.y, accO[4*q+1]);
      accO[4*q+2] = fmaf(xv, w.z, accO[4*q+2]);
      accO[4*q+3] = fmaf(xv, w.w, accO[4*q+3]);
    }
  }

  if (wave == 1 || wave == 3){
    float* buf = (wave==1) ? red0 : red1;
    float4* bp = (float4*)(buf + lane*128);
    #pragma unroll
    for (int q=0;q<16;q++) bp[q]    = make_float4(accS[4*q],accS[4*q+1],accS[4*q+2],accS[4*q+3]);
    #pragma unroll
    for (int q=0;q<16;q++) bp[16+q] = make_float4(accO[4*q],accO[4*q+1],accO[4*q+2],accO[4*q+3]);
  }
  __syncthreads();
  if (wave == 0 || wave == 2){
    const float* buf = (wave==0) ? red0 : red1;
    const float4* bp = (const float4*)(buf + lane*128);
    #pragma unroll
    for (int q=0;q<16;q++){ float4 v = bp[q];    accS[4*q]+=v.x; accS[4*q+1]+=v.y; accS[4*q+2]+=v.z; accS[4*q+3]+=v.w; }
    #pragma unroll
    for (int q=0;q<16;q++){ float4 v = bp[16+q]; accO[4*q]+=v.x; accO[4*q+1]+=v.y; accO[4*q+2]+=v.z; accO[4*q+3]+=v.w; }
  }
  __syncthreads();
  if (wave == 2){
    float4* bp = (float4*)(red0 + lane*128);
    #pragma unroll
    for (int q=0;q<16;q++) bp[q]    = make_float4(accS[4*q],accS[4*q+1],accS[4*q+2],accS[4*q+3]);
    #pragma unroll
    for (int q=0;q<16;q++) bp[16+q] = make_float4(accO[4*q],accO[4*q+1],accO[4*q+2],accO[4*q+3]);
  }
  __syncthreads();
  if (wave == 0){
    const float4* bp = (const float4*)(red0 + lane*128);
    #pragma unroll
    for (int q=0;q<16;q++){ float4 v = bp[q];    accS[4*q]+=v.x; accS[4*q+1]+=v.y; accS[4*q+2]+=v.z; accS[4*q+3]+=v.w; }
    #pragma unroll
    for (int q=0;q<16;q++){ float4 v = bp[16+q]; accO[4*q]+=v.x; accO[4*q+1]+=v.y; accO[4*q+2]+=v.z; accO[4*q+3]+=v.w; }
    #pragma unroll
    for (int j=0;j<64;j++){
      float hs = accS[j] + bs1[j]; hs = hs > 0.f ? hs : 0.f;
      red1[j*64 + lane] = hs;
      float ho = accO[j] + bo1[j]; ho = ho > 0.f ? ho : 0.f;
      red1[(64+j)*64 + lane] = ho;
    }
  }
  __syncthreads();

  {
    const int r2   = tid & 63;
    const int g    = tid >> 6;
    const int head = g >> 1;
    const int jj0  = (g & 1) * 32;
    const float* W2 = head ? Wo2 : Ws2;
    const float* bb = head ? bo2 : bs2;
    float acc2[32];
    #pragma unroll
    for (int c=0;c<32;c++) acc2[c] = bb[jj0+c];
    #pragma unroll 1
    for (int d=0; d<64; d++){
      float hv = red1[(head*64 + d)*64 + r2];
      const float* w2p = W2 + d*64 + jj0;
      #pragma unroll
      for (int c=0;c<32;c++) acc2[c] = fmaf(hv, w2p[c], acc2[c]);
    }
    float* op = (head ? obj : subj) + (size_t)(blockIdx.x*64 + r2)*HID + jj0;
    #pragma unroll
    for (int q=0;q<8;q++)
      ((float4*)op)[q] = make_float4(acc2[4*q],acc2[4*q+1],acc2[4*q+2],acc2[4*q+3]);
  }
}

// ---------------------------------------------------------------------------
// Kernel B0: per-batch sampled FLOOR. 64th largest of (15 subj rows x all
// objects), truncated to 16-bit prefix. Subset 64th <= full 64th, so L[b] is
// always a valid lower bound on the true 64th key.
// ---------------------------------------------------------------------------
__global__ __launch_bounds__(256, 1) void sample_thresh(
    const float* __restrict__ subj, const float* __restrict__ obj,
    uint32_t* __restrict__ L)
{
  __shared__ float sRows[SROWS*HID];
  __shared__ uint32_t keys[SROWS*NN];
  __shared__ uint32_t hist[256];
  __shared__ uint32_t sb[2];
  const int b = blockIdx.x, tid = threadIdx.x;

  const float4* sp = (const float4*)(subj + (size_t)b*NN*HID);
  if (tid < SROWS*16) ((float4*)sRows)[tid] = sp[tid];
  __syncthreads();

  for (int j = tid; j < NN; j += 256){
    const float4* op4 = (const float4*)(obj + ((size_t)b*NN + j)*HID);
    float4 o[16];
    #pragma unroll
    for (int q=0;q<16;q++) o[q] = op4[q];
    #pragma unroll 1
    for (int i=0;i<SROWS;i++){
      const float4* s4 = (const float4*)(sRows + i*HID);
      float acc = 0.f;
      #pragma unroll
      for (int q=0;q<16;q++){
        float4 s = s4[q];
        acc = fmaf(s.x, o[q].x, acc); acc = fmaf(s.y, o[q].y, acc);
        acc = fmaf(s.z, o[q].z, acc); acc = fmaf(s.w, o[q].w, acc);
      }
      keys[i*NN + j] = f2key(acc);
    }
  }
  __syncthreads();

  uint32_t prefix = 0; int remaining = 64;
  for (int round = 0; round < 2; round++){
    const int shift = 24 - round*8;
    hist[tid] = 0;
    __syncthreads();
    for (int idx = tid; idx < SROWS*NN; idx += 256){
      uint32_t k = keys[idx];
      bool match = (round == 0) || ((k >> 24) == (prefix >> 24));
      if (match) atomicAdd(&hist[(k >> shift) & 255u], 1u);
    }
    __syncthreads();
    if (tid == 0){
      uint32_t cum = 0; int bin = 255;
      for (;; bin--){ cum += hist[bin]; if (cum >= (uint32_t)remaining || bin == 0) break; }
      sb[0] = (uint32_t)bin;
      sb[1] = (uint32_t)(remaining - (int)(cum - hist[bin]));
    }
    __syncthreads();
    prefix |= sb[0] << shift;
    remaining = (int)sb[1];
    __syncthreads();
  }
  if (tid == 0) L[b] = prefix;
}

// ---------------------------------------------------------------------------
// Kernel B1: 128x128 score tiles. For keys >= L[b]: 12-bit-prefix histogram
// (exact, complete even if cand overflows) + candidate append via two-phase
// reservation (1 global atomic per block).
// ---------------------------------------------------------------------------
__global__ __launch_bounds__(256, 2) void score_pass1(
    const float* __restrict__ subj, const float* __restrict__ obj,
    const uint32_t* __restrict__ L, uint32_t* __restrict__ cnt,
    uint2* __restrict__ cand, uint32_t* __restrict__ ghist)
{
  __shared__ float sS[128*64];        // 32 KB
  __shared__ float oT[64*128];        // 32 KB
  __shared__ uint32_t hist[NBIN];     // 16 KB
  __shared__ uint32_t lcnt, gbase;
  const int blk = blockIdx.x;
  const int b   = blk >> 6;
  const int t   = blk & 63;
  const int ti  = (t >> 3) << 7;
  const int tj  = (t & 7)  << 7;
  const int tid = threadIdx.x;

  for (int i = tid; i < NBIN; i += 256) hist[i] = 0;
  if (tid == 0) lcnt = 0;
  {
    const float4* gp = (const float4*)subj;
    #pragma unroll
    for (int it=0; it<8; it++){
      int u = tid + it*256;
      int r = u >> 4, k4 = u & 15;
      int gr = b*NN + ti + r; gr = gr < ROWS ? gr : (ROWS-1);
      ((float4*)sS)[r*16 + k4] = gp[(size_t)gr*16 + k4];
    }
  }
  {
    const float4* gp = (const float4*)obj;
    #pragma unroll
    for (int it=0; it<8; it++){
      int u = tid + it*256;
      int r = u >> 4, k4 = u & 15;
      int gr = b*NN + tj + r; gr = gr < ROWS ? gr : (ROWS-1);
      float4 v = gp[(size_t)gr*16 + k4];
      oT[(k4*4+0)*128 + r] = v.x;
      oT[(k4*4+1)*128 + r] = v.y;
      oT[(k4*4+2)*128 + r] = v.z;
      oT[(k4*4+3)*128 + r] = v.w;
    }
  }
  __syncthreads();

  const int tx = tid & 15, ty = tid >> 4;
  float acc[8][8];
  #pragma unroll
  for (int a=0;a<8;a++)
    #pragma unroll
    for (int c=0;c<8;c++) acc[a][c] = 0.f;

  #pragma unroll 2
  for (int k=0;k<64;k++){
    float s[8];
    #pragma unroll
    for (int a=0;a<8;a++) s[a] = sS[(ty*8+a)*64 + k];
    float4 o0 = *(const float4*)&oT[k*128 + tx*8];
    float4 o1 = *(const float4*)&oT[k*128 + tx*8 + 4];
    float o[8] = {o0.x,o0.y,o0.z,o0.w,o1.x,o1.y,o1.z,o1.w};
    #pragma unroll
    for (int a=0;a<8;a++)
      #pragma unroll
      for (int c=0;c<8;c++)
        acc[a][c] = fmaf(s[a], o[c], acc[a][c]);
  }

  const uint32_t Lb = L[b];
  int myCnt = 0;
  #pragma unroll
  for (int a=0;a<8;a++){
    int gi = ti + ty*8 + a;
    #pragma unroll
    for (int c=0;c<8;c++){
      int gj = tj + tx*8 + c;
      if (gi < NN && gj < NN){
        uint32_t key = f2key(acc[a][c]);
        if (key >= Lb){ myCnt++; atomicAdd(&hist[key >> 20], 1u); }
      }
    }
  }
  uint32_t lbase = atomicAdd(&lcnt, (uint32_t)myCnt);
  __syncthreads();
  if (tid == 0) gbase = atomicAdd(&cnt[b], lcnt);
  __syncthreads();
  uint32_t pos = gbase + lbase;
  #pragma unroll
  for (int a=0;a<8;a++){
    int gi = ti + ty*8 + a;
    #pragma unroll
    for (int c=0;c<8;c++){
      int gj = tj + tx*8 + c;
      if (gi < NN && gj < NN){
        uint32_t key = f2key(acc[a][c]);
        if (key >= Lb){
          if (pos < CAPB) cand[(size_t)b*CAPB + pos] = make_uint2(key, (uint32_t)(gi*NN + gj));
          pos++;
        }
      }
    }
  }
  __syncthreads();
  for (int i = tid; i < NBIN; i += 256){
    uint32_t v = hist[i];
    if (v) atomicAdd(&ghist[(size_t)b*NBIN + i], v);
  }
}

// ---------------------------------------------------------------------------
// Kernel B2: per batch, scan histogram top-down -> exact 12-bit bucket floor
// T[b] of the 64th-largest key; flag[b] = candidate list overflowed.
// ---------------------------------------------------------------------------
__global__ __launch_bounds__(256, 1) void pick_thresh(
    const uint32_t* __restrict__ ghist, const uint32_t* __restrict__ cnt,
    uint32_t* __restrict__ T, uint32_t* __restrict__ flag)
{
  __shared__ uint32_t S[256];
  const int b = blockIdx.x, tid = threadIdx.x;
  const uint32_t* h = ghist + (size_t)b*NBIN;
  uint32_t loc[16];
  uint32_t s = 0;
  #pragma unroll
  for (int i=0;i<16;i++){ loc[i] = h[tid*16 + i]; s += loc[i]; }
  S[tid] = s;
  __syncthreads();
  for (int off = 1; off < 256; off <<= 1){
    uint32_t v = (tid + off < 256) ? S[tid + off] : 0u;
    __syncthreads();
    S[tid] += v;
    __syncthreads();
  }
  uint32_t above = (tid < 255) ? S[tid + 1] : 0u;   // suffix count of chunks > mine
  if (above < 64u && S[tid] >= 64u){
    uint32_t suf = above; int best = 0;
    for (int i=15;i>=0;i--){ suf += loc[i]; if (suf >= 64u){ best = i; break; } }
    T[b] = (uint32_t)(tid*16 + best) << 20;
  }
  if (tid == 0) flag[b] = (cnt[b] > (uint32_t)CAPB) ? 1u : 0u;
}

// ---------------------------------------------------------------------------
// Kernel B3: repair pass — only for overflowed batches. Recompute dots
// (bitwise-identical order), keep keys >= exact T[b] into cand (reused)
// with counter cnt2. Early-exits when flag==0 (common case).
// ---------------------------------------------------------------------------
__global__ __launch_bounds__(256, 2) void score_repair(
    const float* __restrict__ subj, const float* __restrict__ obj,
    const uint32_t* __restrict__ T, const uint32_t* __restrict__ flag,
    uint32_t* __restrict__ cnt2, uint2* __restrict__ cand)
{
  const int blk = blockIdx.x;
  const int b   = blk >> 6;
  if (flag[b] == 0u) return;

  __shared__ float sS[128*64];
  __shared__ float oT[64*128];
  __shared__ uint32_t lcnt, gbase;
  const int t   = blk & 63;
  const int ti  = (t >> 3) << 7;
  const int tj  = (t & 7)  << 7;
  const int tid = threadIdx.x;

  if (tid == 0) lcnt = 0;
  {
    const float4* gp = (const float4*)subj;
    #pragma unroll
    for (int it=0; it<8; it++){
      int u = tid + it*256;
      int r = u >> 4, k4 = u & 15;
      int gr = b*NN + ti + r; gr = gr < ROWS ? gr : (ROWS-1);
      ((float4*)sS)[r*16 + k4] = gp[(size_t)gr*16 + k4];
    }
  }
  {
    const float4* gp = (const float4*)obj;
    #pragma unroll
    for (int it=0; it<8; it++){
      int u = tid + it*256;
      int r = u >> 4, k4 = u & 15;
      int gr = b*NN + tj + r; gr = gr < ROWS ? gr : (ROWS-1);
      float4 v = gp[(size_t)gr*16 + k4];
      oT[(k4*4+0)*128 + r] = v.x;
      oT[(k4*4+1)*128 + r] = v.y;
      oT[(k4*4+2)*128 + r] = v.z;
      oT[(k4*4+3)*128 + r] = v.w;
    }
  }
  __syncthreads();

  const int tx = tid & 15, ty = tid >> 4;
  float acc[8][8];
  #pragma unroll
  for (int a=0;a<8;a++)
    #pragma unroll
    for (int c=0;c<8;c++) acc[a][c] = 0.f;

  #pragma unroll 2
  for (int k=0;k<64;k++){
    float s[8];
    #pragma unroll
    for (int a=0;a<8;a++) s[a] = sS[(ty*8+a)*64 + k];
    float4 o0 = *(const float4*)&oT[k*128 + tx*8];
    float4 o1 = *(const float4*)&oT[k*128 + tx*8 + 4];
    float o[8] = {o0.x,o0.y,o0.z,o0.w,o1.x,o1.y,o1.z,o1.w};
    #pragma unroll
    for (int a=0;a<8;a++)
      #pragma unroll
      for (int c=0;c<8;c++)
        acc[a][c] = fmaf(s[a], o[c], acc[a][c]);
  }

  const uint32_t Tb = T[b];
  int myCnt = 0;
  #pragma unroll
  for (int a=0;a<8;a++){
    int gi = ti + ty*8 + a;
    #pragma unroll
    for (int c=0;c<8;c++){
      int gj = tj + tx*8 + c;
      if (gi < NN && gj < NN && f2key(acc[a][c]) >= Tb) myCnt++;
    }
  }
  uint32_t lbase = atomicAdd(&lcnt, (uint32_t)myCnt);
  __syncthreads();
  if (tid == 0) gbase = atomicAdd(&cnt2[b], lcnt);
  __syncthreads();
  uint32_t pos = gbase + lbase;
  #pragma unroll
  for (int a=0;a<8;a++){
    int gi = ti + ty*8 + a;
    #pragma unroll
    for (int c=0;c<8;c++){
      int gj = tj + tx*8 + c;
      if (gi < NN && gj < NN){
        uint32_t key = f2key(acc[a][c]);
        if (key >= Tb){
          if (pos < CAPB) cand[(size_t)b*CAPB + pos] = make_uint2(key, (uint32_t)(gi*NN + gj));
          pos++;
        }
      }
    }
  }
}

// ---------------------------------------------------------------------------
// Kernel C: exact top-64 per batch from the (complete) candidate list.
// 4-round radix-select -> exact 64th key; rank by (value desc, index asc)
// matching jax.lax.top_k tie semantics. Sigmoid on winners only.
// ---------------------------------------------------------------------------
__global__ __launch_bounds__(256, 1) void final_select(
    const uint32_t* __restrict__ cnt, const uint32_t* __restrict__ cnt2,
    const uint32_t* __restrict__ flag, const uint2* __restrict__ cand,
    float* __restrict__ out)
{
  __shared__ uint32_t keys[CAPB];
  __shared__ uint32_t hist[256];
  __shared__ uint32_t sb[2];
  __shared__ uint2 win[192];
  __shared__ uint32_t wn;
  const int b = blockIdx.x, tid = threadIdx.x;
  uint32_t n0 = flag[b] ? cnt2[b] : cnt[b];
  const int n = (n0 < (uint32_t)CAPB) ? (int)n0 : CAPB;

  for (int i = tid; i < n; i += 256) keys[i] = cand[(size_t)b*CAPB + i].x;
  if (tid == 0) wn = 0;
  __syncthreads();

  uint32_t prefix = 0; int remaining = 64;
  for (int round = 0; round < 4; round++){
    const int shift = 24 - round*8;
    hist[tid] = 0;
    __syncthreads();
    for (int i = tid; i < n; i += 256){
      uint32_t k = keys[i];
      bool match = (round == 0) || ((k >> (shift+8)) == (prefix >> (shift+8)));
      if (match) atomicAdd(&hist[(k >> shift) & 255u], 1u);
    }
    __syncthreads();
    if (tid == 0){
      uint32_t cum = 0; int bin = 255;
      for (;; bin--){ cum += hist[bin]; if (cum >= (uint32_t)remaining || bin == 0) break; }
      sb[0] = (uint32_t)bin;
      sb[1] = (uint32_t)(remaining - (int)(cum - hist[bin]));
    }
    __syncthreads();
    prefix |= sb[0] << shift;
    remaining = (int)sb[1];
    __syncthreads();
  }
  const uint32_t Tk = prefix;

  for (int i = tid; i < n; i += 256){
    if (keys[i] >= Tk){
      uint32_t p = atomicAdd(&wn, 1u);
      if (p < 192u) win[p] = make_uint2(keys[i], cand[(size_t)b*CAPB + i].y);
    }
  }
  __syncthreads();
  const int m = (wn < 192u) ? (int)wn : 192;

  if (tid < m){
    const uint64_t me = ((uint64_t)win[tid].x << 32) | (uint64_t)(uint32_t)(~win[tid].y);
    int rank = 0;
    for (int s = 0; s < m; s++){
      uint64_t oth = ((uint64_t)win[s].x << 32) | (uint64_t)(uint32_t)(~win[s].y);
      rank += (oth > me) ? 1 : 0;
    }
    if (rank < 64){
      const uint32_t f = win[tid].y;
      const float d  = key2f(win[tid].x);
      const float sc = 1.0f / (1.0f + expf(-d));
      out[((size_t)b*64 + rank)*2 + 0] = (float)(f / NN);
      out[((size_t)b*64 + rank)*2 + 1] = (float)(f % NN);
      out[(size_t)NB*64*2 + (size_t)b*64 + rank] = sc;
    }
  }
}

// ---------------------------------------------------------------------------
extern "C" void kernel_launch(void* const* d_in, const int* in_sizes, int n_in,
                              void* d_out, int out_size, void* d_ws, size_t ws_size,
                              hipStream_t stream) {
  const float* x   = (const float*)d_in[0];
  const float* Ws1 = (const float*)d_in[2];
  const float* bs1 = (const float*)d_in[3];
  const float* Ws2 = (const float*)d_in[4];
  const float* bs2 = (const float*)d_in[5];
  const float* Wo1 = (const float*)d_in[6];
  const float* bo1 = (const float*)d_in[7];
  const float* Wo2 = (const float*)d_in[8];
  const float* bo2 = (const float*)d_in[9];
  float* out = (float*)d_out;

  char* ws = (char*)d_ws;
  float*    subj = (float*)ws;                        //  8,192,000 B
  float*    objp = (float*)(ws + 8192000);            //  8,192,000 B
  uint32_t* L    = (uint32_t*)(ws + 16384000);        //        128 B
  uint32_t* cnt  = (uint32_t*)(ws + 16384128);        //        128 B
  uint32_t* cnt2 = (uint32_t*)(ws + 16384256);        //        128 B
  uint32_t* ghist= (uint32_t*)(ws + 16384384);        //    524,288 B
  uint32_t* T    = (uint32_t*)(ws + 16908672);        //        128 B
  uint32_t* flag = (uint32_t*)(ws + 16908800);        //        128 B
  uint2*    cand = (uint2*)   (ws + 16908928);        //  3,932,160 B  (~20.8 MB total)

  // zero cnt + cnt2 + ghist in one contiguous memset
  hipMemsetAsync(cnt, 0, 128 + 128 + 524288, stream);

  mlp_kernel<<<ROWS/64, 256, 0, stream>>>(x, Ws1, bs1, Ws2, bs2,
                                          Wo1, bo1, Wo2, bo2, subj, objp);
  sample_thresh<<<NB, 256, 0, stream>>>(subj, objp, L);
  score_pass1<<<NB*64, 256, 0, stream>>>(subj, objp, L, cnt, cand, ghist);
  pick_thresh<<<NB, 256, 0, stream>>>(ghist, cnt, T, flag);
  score_repair<<<NB*64, 256, 0, stream>>>(subj, objp, T, flag, cnt2, cand);
  final_select<<<NB, 256, 0, stream>>>(cnt, cnt2, flag, cand, out);
}

// Round 3
// 743.079 us; speedup vs baseline: 1.5896x; 1.5896x over previous
//
#include <hip/hip_runtime.h>
#include <cstdint>

#define NB 32
#define NN 1000
#define NC 1601
#define HID 64
#define ROWS (NB*NN)       // 32000
#define CAPB 15360         // candidate cap per batch
#define SROWS 15           // sample rows for threshold floor
#define NBIN 4096          // 12-bit key-prefix histogram
#define KCH 32             // mlp k-chunk
#define XSTR 68            // 64 rows + 4 pad (16B-aligned b128 reads)
#define SSTR 132           // score tile row stride: 128 + 4 pad

__device__ __forceinline__ uint32_t f2key(float f){
  uint32_t u = __float_as_uint(f);
  return (u & 0x80000000u) ? ~u : (u | 0x80000000u);   // monotone float->uint
}
__device__ __forceinline__ float key2f(uint32_t k){
  uint32_t u = (k & 0x80000000u) ? (k & 0x7fffffffu) : ~k;
  return __uint_as_float(u);
}

// ---------------------------------------------------------------------------
// Kernel A: fused 2-layer MLP, tiled GEMM.
// Block = 64 rows, 256 threads: tx=col-group (4 subj + 4 obj cols), ty=row
// group (4 rows). x staged coalesced -> LDS transposed xT[k][row] (double
// buffered); W1/W2 read per-k as float4 (L1 broadcast across ty). Layer-2
// h round-trips LDS transposed. Sum order: k ascending, single chain.
// ---------------------------------------------------------------------------
__global__ __launch_bounds__(256, 4) void mlp_kernel(
    const float* __restrict__ x,
    const float* __restrict__ Ws1, const float* __restrict__ bs1,
    const float* __restrict__ Ws2, const float* __restrict__ bs2,
    const float* __restrict__ Wo1, const float* __restrict__ bo1,
    const float* __restrict__ Wo2, const float* __restrict__ bo2,
    float* __restrict__ subj, float* __restrict__ obj)
{
  __shared__ float smem[2*KCH*XSTR];   // 17408 B; reused as hT[64][68]
  __shared__ float xtail[64];
  const int tid = threadIdx.x;
  const int tx  = tid & 15;            // cols tx*4..+3 (per head)
  const int ty  = tid >> 4;            // rows ty*4..+3
  const int row0 = blockIdx.x * 64;

  float accS[4][4], accO[4][4];
  #pragma unroll
  for (int r=0;r<4;r++)
    #pragma unroll
    for (int c=0;c<4;c++){ accS[r][c]=0.f; accO[r][c]=0.f; }

  // prologue: load chunk 0 into regs (coalesced: 32 lanes = one row segment)
  float stg[8];
  #pragma unroll
  for (int it=0; it<8; it++){
    int u = tid + it*256;
    stg[it] = x[(size_t)(row0 + (u>>5))*NC + (u&31)];
  }

  const int NCHUNK = 50;               // 50*32 = 1600, tail k=1600 after
  for (int c = 0; c < NCHUNK; c++){
    float* xT = smem + (c & 1)*(KCH*XSTR);
    #pragma unroll
    for (int it=0; it<8; it++){
      int u = tid + it*256;
      xT[(u&31)*XSTR + (u>>5)] = stg[it];
    }
    __syncthreads();                   // buffer c ready; buffer c^1 free
    if (c+1 < NCHUNK){
      const int k0n = (c+1)*KCH;
      #pragma unroll
      for (int it=0; it<8; it++){      // global latency hidden by compute(c)
        int u = tid + it*256;
        stg[it] = x[(size_t)(row0 + (u>>5))*NC + k0n + (u&31)];
      }
    }
    const float* wS = Ws1 + (size_t)(c*KCH)*HID + tx*4;
    const float* wO = Wo1 + (size_t)(c*KCH)*HID + tx*4;
    #pragma unroll 4
    for (int k=0; k<KCH; k++){
      float4 a  = *(const float4*)&xT[k*XSTR + ty*4];    // broadcast, no conflict
      float4 bS = *(const float4*)(wS + k*HID);
      float4 bO = *(const float4*)(wO + k*HID);
      float av[4] = {a.x,a.y,a.z,a.w};
      float bs[4] = {bS.x,bS.y,bS.z,bS.w};
      float bo[4] = {bO.x,bO.y,bO.z,bO.w};
      #pragma unroll
      for (int r=0;r<4;r++)
        #pragma unroll
        for (int c2=0;c2<4;c2++){
          accS[r][c2] = fmaf(av[r], bs[c2], accS[r][c2]);
          accO[r][c2] = fmaf(av[r], bo[c2], accO[r][c2]);
        }
    }
  }

  // tail k = 1600
  if (tid < 64) xtail[tid] = x[(size_t)(row0 + tid)*NC + 1600];
  __syncthreads();
  {
    float4 a  = *(const float4*)&xtail[ty*4];
    float4 bS = *(const float4*)(Ws1 + (size_t)1600*HID + tx*4);
    float4 bO = *(const float4*)(Wo1 + (size_t)1600*HID + tx*4);
    float av[4] = {a.x,a.y,a.z,a.w};
    float bs[4] = {bS.x,bS.y,bS.z,bS.w};
    float bo[4] = {bO.x,bO.y,bO.z,bO.w};
    #pragma unroll
    for (int r=0;r<4;r++)
      #pragma unroll
      for (int c2=0;c2<4;c2++){
        accS[r][c2] = fmaf(av[r], bs[c2], accS[r][c2]);
        accO[r][c2] = fmaf(av[r], bo[c2], accO[r][c2]);
      }
  }

  // ---- layer 2, one head at a time through hT[64][68] (reuses smem) ----
  float* hT = smem;
  #pragma unroll 1
  for (int head = 0; head < 2; head++){
    const float* b1 = head ? bo1 : bs1;
    const float* b2 = head ? bo2 : bs2;
    const float* W2 = head ? Wo2 : Ws2;
    float* yout     = head ? obj : subj;
    __syncthreads();                   // all xT / previous-head hT reads done
    #pragma unroll
    for (int jj=0; jj<4; jj++){
      float bias = b1[tx*4 + jj];
      float4 hv;
      hv.x = fmaxf((head ? accO[0][jj] : accS[0][jj]) + bias, 0.f);
      hv.y = fmaxf((head ? accO[1][jj] : accS[1][jj]) + bias, 0.f);
      hv.z = fmaxf((head ? accO[2][jj] : accS[2][jj]) + bias, 0.f);
      hv.w = fmaxf((head ? accO[3][jj] : accS[3][jj]) + bias, 0.f);
      *(float4*)&hT[(tx*4+jj)*XSTR + ty*4] = hv;
    }
    __syncthreads();
    float accY[4][4];
    #pragma unroll
    for (int c2=0;c2<4;c2++){
      float bv = b2[tx*4 + c2];
      #pragma unroll
      for (int r=0;r<4;r++) accY[r][c2] = bv;
    }
    #pragma unroll 4
    for (int d=0; d<64; d++){
      float4 a = *(const float4*)&hT[d*XSTR + ty*4];
      float4 w = *(const float4*)(W2 + d*HID + tx*4);
      float av[4] = {a.x,a.y,a.z,a.w};
      float wv[4] = {w.x,w.y,w.z,w.w};
      #pragma unroll
      for (int r=0;r<4;r++)
        #pragma unroll
        for (int c2=0;c2<4;c2++)
          accY[r][c2] = fmaf(av[r], wv[c2], accY[r][c2]);
    }
    #pragma unroll
    for (int r=0;r<4;r++)
      *(float4*)&yout[(size_t)(row0 + ty*4 + r)*HID + tx*4] =
        make_float4(accY[r][0], accY[r][1], accY[r][2], accY[r][3]);
  }
}

// ---------------------------------------------------------------------------
// Kernel B0: per-batch sampled FLOOR (unchanged). Subset 64th <= full 64th.
// ---------------------------------------------------------------------------
__global__ __launch_bounds__(256, 1) void sample_thresh(
    const float* __restrict__ subj, const float* __restrict__ obj,
    uint32_t* __restrict__ L)
{
  __shared__ float sRows[SROWS*HID];
  __shared__ uint32_t keys[SROWS*NN];
  __shared__ uint32_t hist[256];
  __shared__ uint32_t sb[2];
  const int b = blockIdx.x, tid = threadIdx.x;

  const float4* sp = (const float4*)(subj + (size_t)b*NN*HID);
  if (tid < SROWS*16) ((float4*)sRows)[tid] = sp[tid];
  __syncthreads();

  for (int j = tid; j < NN; j += 256){
    const float4* op4 = (const float4*)(obj + ((size_t)b*NN + j)*HID);
    float4 o[16];
    #pragma unroll
    for (int q=0;q<16;q++) o[q] = op4[q];
    #pragma unroll 1
    for (int i=0;i<SROWS;i++){
      const float4* s4 = (const float4*)(sRows + i*HID);
      float acc = 0.f;
      #pragma unroll
      for (int q=0;q<16;q++){
        float4 s = s4[q];
        acc = fmaf(s.x, o[q].x, acc); acc = fmaf(s.y, o[q].y, acc);
        acc = fmaf(s.z, o[q].z, acc); acc = fmaf(s.w, o[q].w, acc);
      }
      keys[i*NN + j] = f2key(acc);
    }
  }
  __syncthreads();

  uint32_t prefix = 0; int remaining = 64;
  for (int round = 0; round < 2; round++){
    const int shift = 24 - round*8;
    hist[tid] = 0;
    __syncthreads();
    for (int idx = tid; idx < SROWS*NN; idx += 256){
      uint32_t k = keys[idx];
      bool match = (round == 0) || ((k >> 24) == (prefix >> 24));
      if (match) atomicAdd(&hist[(k >> shift) & 255u], 1u);
    }
    __syncthreads();
    if (tid == 0){
      uint32_t cum = 0; int bin = 255;
      for (;; bin--){ cum += hist[bin]; if (cum >= (uint32_t)remaining || bin == 0) break; }
      sb[0] = (uint32_t)bin;
      sb[1] = (uint32_t)(remaining - (int)(cum - hist[bin]));
    }
    __syncthreads();
    prefix |= sb[0] << shift;
    remaining = (int)sb[1];
    __syncthreads();
  }
  if (tid == 0) L[b] = prefix;
}

// ---------------------------------------------------------------------------
// Shared tile-compute for B1/B3: 128x128 tile, k staged in 2 chunks of 32,
// both tiles k-major stride 132 -> b128 fragment reads (broadcast / 4-way).
// FMA chains k-ascending: bitwise-identical across B1 and B3.
// ---------------------------------------------------------------------------
__device__ __forceinline__ void score_tile_acc(
    const float* __restrict__ subj, const float* __restrict__ obj,
    int b, int ti, int tj, int tid,
    float* __restrict__ sT, float* __restrict__ oT, float (&acc)[8][8])
{
  const int tx = tid & 15, ty = tid >> 4;
  #pragma unroll
  for (int a=0;a<8;a++)
    #pragma unroll
    for (int c=0;c<8;c++) acc[a][c] = 0.f;

  #pragma unroll 1
  for (int half = 0; half < 2; half++){
    __syncthreads();                   // previous chunk's reads done
    {
      const float4* gp = (const float4*)subj;
      #pragma unroll
      for (int it=0; it<4; it++){
        int u = tid + it*256;
        int r = u >> 3, q = (u & 7) + half*8;
        int gr = b*NN + ti + r; gr = gr < ROWS ? gr : (ROWS-1);
        float4 v = gp[(size_t)gr*16 + q];
        int kk = (u & 7)*4;
        sT[(kk+0)*SSTR + r] = v.x;
        sT[(kk+1)*SSTR + r] = v.y;
        sT[(kk+2)*SSTR + r] = v.z;
        sT[(kk+3)*SSTR + r] = v.w;
      }
      const float4* gp2 = (const float4*)obj;
      #pragma unroll
      for (int it=0; it<4; it++){
        int u = tid + it*256;
        int r = u >> 3, q = (u & 7) + half*8;
        int gr = b*NN + tj + r; gr = gr < ROWS ? gr : (ROWS-1);
        float4 v = gp2[(size_t)gr*16 + q];
        int kk = (u & 7)*4;
        oT[(kk+0)*SSTR + r] = v.x;
        oT[(kk+1)*SSTR + r] = v.y;
        oT[(kk+2)*SSTR + r] = v.z;
        oT[(kk+3)*SSTR + r] = v.w;
      }
    }
    __syncthreads();
    #pragma unroll 2
    for (int k=0; k<32; k++){
      float4 s0 = *(const float4*)&sT[k*SSTR + ty*8];
      float4 s1 = *(const float4*)&sT[k*SSTR + ty*8 + 4];
      float4 o0 = *(const float4*)&oT[k*SSTR + tx*8];
      float4 o1 = *(const float4*)&oT[k*SSTR + tx*8 + 4];
      float s[8] = {s0.x,s0.y,s0.z,s0.w,s1.x,s1.y,s1.z,s1.w};
      float o[8] = {o0.x,o0.y,o0.z,o0.w,o1.x,o1.y,o1.z,o1.w};
      #pragma unroll
      for (int a=0;a<8;a++)
        #pragma unroll
        for (int c=0;c<8;c++)
          acc[a][c] = fmaf(s[a], o[c], acc[a][c]);
    }
  }
}

// ---------------------------------------------------------------------------
// Kernel B1: score tiles; 12-bit histogram of keys >= L[b] + candidate
// append via two-phase reservation (1 global atomic per block).
// ---------------------------------------------------------------------------
__global__ __launch_bounds__(256, 3) void score_pass1(
    const float* __restrict__ subj, const float* __restrict__ obj,
    const uint32_t* __restrict__ L, uint32_t* __restrict__ cnt,
    uint2* __restrict__ cand, uint32_t* __restrict__ ghist)
{
  __shared__ float sT[32*SSTR];       // 16896 B
  __shared__ float oT[32*SSTR];       // 16896 B
  __shared__ uint32_t hist[NBIN];     // 16384 B
  __shared__ uint32_t lcnt, gbase;
  const int blk = blockIdx.x;
  const int b   = blk >> 6;
  const int t   = blk & 63;
  const int ti  = (t >> 3) << 7;
  const int tj  = (t & 7)  << 7;
  const int tid = threadIdx.x;
  const int tx = tid & 15, ty = tid >> 4;

  for (int i = tid; i < NBIN; i += 256) hist[i] = 0;
  if (tid == 0) lcnt = 0;

  float acc[8][8];
  score_tile_acc(subj, obj, b, ti, tj, tid, sT, oT, acc);

  const uint32_t Lb = L[b];
  int myCnt = 0;
  #pragma unroll
  for (int a=0;a<8;a++){
    int gi = ti + ty*8 + a;
    #pragma unroll
    for (int c=0;c<8;c++){
      int gj = tj + tx*8 + c;
      if (gi < NN && gj < NN){
        uint32_t key = f2key(acc[a][c]);
        if (key >= Lb){ myCnt++; atomicAdd(&hist[key >> 20], 1u); }
      }
    }
  }
  uint32_t lbase = atomicAdd(&lcnt, (uint32_t)myCnt);
  __syncthreads();
  if (tid == 0) gbase = atomicAdd(&cnt[b], lcnt);
  __syncthreads();
  uint32_t pos = gbase + lbase;
  #pragma unroll
  for (int a=0;a<8;a++){
    int gi = ti + ty*8 + a;
    #pragma unroll
    for (int c=0;c<8;c++){
      int gj = tj + tx*8 + c;
      if (gi < NN && gj < NN){
        uint32_t key = f2key(acc[a][c]);
        if (key >= Lb){
          if (pos < CAPB) cand[(size_t)b*CAPB + pos] = make_uint2(key, (uint32_t)(gi*NN + gj));
          pos++;
        }
      }
    }
  }
  __syncthreads();
  for (int i = tid; i < NBIN; i += 256){
    uint32_t v = hist[i];
    if (v) atomicAdd(&ghist[(size_t)b*NBIN + i], v);
  }
}

// ---------------------------------------------------------------------------
// Kernel B2: exact 12-bit bucket floor T[b] of the 64th-largest key;
// flag[b] = candidate overflow.
// ---------------------------------------------------------------------------
__global__ __launch_bounds__(256, 1) void pick_thresh(
    const uint32_t* __restrict__ ghist, const uint32_t* __restrict__ cnt,
    uint32_t* __restrict__ T, uint32_t* __restrict__ flag)
{
  __shared__ uint32_t S[256];
  const int b = blockIdx.x, tid = threadIdx.x;
  const uint32_t* h = ghist + (size_t)b*NBIN;
  uint32_t loc[16];
  uint32_t s = 0;
  #pragma unroll
  for (int i=0;i<16;i++){ loc[i] = h[tid*16 + i]; s += loc[i]; }
  S[tid] = s;
  __syncthreads();
  for (int off = 1; off < 256; off <<= 1){
    uint32_t v = (tid + off < 256) ? S[tid + off] : 0u;
    __syncthreads();
    S[tid] += v;
    __syncthreads();
  }
  uint32_t above = (tid < 255) ? S[tid + 1] : 0u;
  if (above < 64u && S[tid] >= 64u){
    uint32_t suf = above; int best = 0;
    for (int i=15;i>=0;i--){ suf += loc[i]; if (suf >= 64u){ best = i; break; } }
    T[b] = (uint32_t)(tid*16 + best) << 20;
  }
  if (tid == 0) flag[b] = (cnt[b] > (uint32_t)CAPB) ? 1u : 0u;
}

// ---------------------------------------------------------------------------
// Kernel B3: repair pass for overflowed batches (early-exit common case).
// Identical dot chains to B1.
// ---------------------------------------------------------------------------
__global__ __launch_bounds__(256, 3) void score_repair(
    const float* __restrict__ subj, const float* __restrict__ obj,
    const uint32_t* __restrict__ T, const uint32_t* __restrict__ flag,
    uint32_t* __restrict__ cnt2, uint2* __restrict__ cand)
{
  const int blk = blockIdx.x;
  const int b   = blk >> 6;
  if (flag[b] == 0u) return;

  __shared__ float sT[32*SSTR];
  __shared__ float oT[32*SSTR];
  __shared__ uint32_t lcnt, gbase;
  const int t   = blk & 63;
  const int ti  = (t >> 3) << 7;
  const int tj  = (t & 7)  << 7;
  const int tid = threadIdx.x;
  const int tx = tid & 15, ty = tid >> 4;

  if (tid == 0) lcnt = 0;

  float acc[8][8];
  score_tile_acc(subj, obj, b, ti, tj, tid, sT, oT, acc);

  const uint32_t Tb = T[b];
  int myCnt = 0;
  #pragma unroll
  for (int a=0;a<8;a++){
    int gi = ti + ty*8 + a;
    #pragma unroll
    for (int c=0;c<8;c++){
      int gj = tj + tx*8 + c;
      if (gi < NN && gj < NN && f2key(acc[a][c]) >= Tb) myCnt++;
    }
  }
  uint32_t lbase = atomicAdd(&lcnt, (uint32_t)myCnt);
  __syncthreads();
  if (tid == 0) gbase = atomicAdd(&cnt2[b], lcnt);
  __syncthreads();
  uint32_t pos = gbase + lbase;
  #pragma unroll
  for (int a=0;a<8;a++){
    int gi = ti + ty*8 + a;
    #pragma unroll
    for (int c=0;c<8;c++){
      int gj = tj + tx*8 + c;
      if (gi < NN && gj < NN){
        uint32_t key = f2key(acc[a][c]);
        if (key >= Tb){
          if (pos < CAPB) cand[(size_t)b*CAPB + pos] = make_uint2(key, (uint32_t)(gi*NN + gj));
          pos++;
        }
      }
    }
  }
}

// ---------------------------------------------------------------------------
// Kernel C: exact top-64 per batch. Radix-select 64th key, rank by
// (value desc, index asc) = jax.lax.top_k tie semantics.
// ---------------------------------------------------------------------------
__global__ __launch_bounds__(256, 1) void final_select(
    const uint32_t* __restrict__ cnt, const uint32_t* __restrict__ cnt2,
    const uint32_t* __restrict__ flag, const uint2* __restrict__ cand,
    float* __restrict__ out)
{
  __shared__ uint32_t keys[CAPB];
  __shared__ uint32_t hist[256];
  __shared__ uint32_t sb[2];
  __shared__ uint2 win[192];
  __shared__ uint32_t wn;
  const int b = blockIdx.x, tid = threadIdx.x;
  uint32_t n0 = flag[b] ? cnt2[b] : cnt[b];
  const int n = (n0 < (uint32_t)CAPB) ? (int)n0 : CAPB;

  for (int i = tid; i < n; i += 256) keys[i] = cand[(size_t)b*CAPB + i].x;
  if (tid == 0) wn = 0;
  __syncthreads();

  uint32_t prefix = 0; int remaining = 64;
  for (int round = 0; round < 4; round++){
    const int shift = 24 - round*8;
    hist[tid] = 0;
    __syncthreads();
    for (int i = tid; i < n; i += 256){
      uint32_t k = keys[i];
      bool match = (round == 0) || ((k >> (shift+8)) == (prefix >> (shift+8)));
      if (match) atomicAdd(&hist[(k >> shift) & 255u], 1u);
    }
    __syncthreads();
    if (tid == 0){
      uint32_t cum = 0; int bin = 255;
      for (;; bin--){ cum += hist[bin]; if (cum >= (uint32_t)remaining || bin == 0) break; }
      sb[0] = (uint32_t)bin;
      sb[1] = (uint32_t)(remaining - (int)(cum - hist[bin]));
    }
    __syncthreads();
    prefix |= sb[0] << shift;
    remaining = (int)sb[1];
    __syncthreads();
  }
  const uint32_t Tk = prefix;

  for (int i = tid; i < n; i += 256){
    if (keys[i] >= Tk){
      uint32_t p = atomicAdd(&wn, 1u);
      if (p < 192u) win[p] = make_uint2(keys[i], cand[(size_t)b*CAPB + i].y);
    }
  }
  __syncthreads();
  const int m = (wn < 192u) ? (int)wn : 192;

  if (tid < m){
    const uint64_t me = ((uint64_t)win[tid].x << 32) | (uint64_t)(uint32_t)(~win[tid].y);
    int rank = 0;
    for (int s = 0; s < m; s++){
      uint64_t oth = ((uint64_t)win[s].x << 32) | (uint64_t)(uint32_t)(~win[s].y);
      rank += (oth > me) ? 1 : 0;
    }
    if (rank < 64){
      const uint32_t f = win[tid].y;
      const float d  = key2f(win[tid].x);
      const float sc = 1.0f / (1.0f + expf(-d));
      out[((size_t)b*64 + rank)*2 + 0] = (float)(f / NN);
      out[((size_t)b*64 + rank)*2 + 1] = (float)(f % NN);
      out[(size_t)NB*64*2 + (size_t)b*64 + rank] = sc;
    }
  }
}

// ---------------------------------------------------------------------------
extern "C" void kernel_launch(void* const* d_in, const int* in_sizes, int n_in,
                              void* d_out, int out_size, void* d_ws, size_t ws_size,
                              hipStream_t stream) {
  const float* x   = (const float*)d_in[0];
  const float* Ws1 = (const float*)d_in[2];
  const float* bs1 = (const float*)d_in[3];
  const float* Ws2 = (const float*)d_in[4];
  const float* bs2 = (const float*)d_in[5];
  const float* Wo1 = (const float*)d_in[6];
  const float* bo1 = (const float*)d_in[7];
  const float* Wo2 = (const float*)d_in[8];
  const float* bo2 = (const float*)d_in[9];
  float* out = (float*)d_out;

  char* ws = (char*)d_ws;
  float*    subj = (float*)ws;                        //  8,192,000 B
  float*    objp = (float*)(ws + 8192000);            //  8,192,000 B
  uint32_t* L    = (uint32_t*)(ws + 16384000);        //        128 B
  uint32_t* cnt  = (uint32_t*)(ws + 16384128);        //        128 B
  uint32_t* cnt2 = (uint32_t*)(ws + 16384256);        //        128 B
  uint32_t* ghist= (uint32_t*)(ws + 16384384);        //    524,288 B
  uint32_t* T    = (uint32_t*)(ws + 16908672);        //        128 B
  uint32_t* flag = (uint32_t*)(ws + 16908800);        //        128 B
  uint2*    cand = (uint2*)   (ws + 16908928);        //  3,932,160 B

  hipMemsetAsync(cnt, 0, 128 + 128 + 524288, stream);

  mlp_kernel<<<ROWS/64, 256, 0, stream>>>(x, Ws1, bs1, Ws2, bs2,
                                          Wo1, bo1, Wo2, bo2, subj, objp);
  sample_thresh<<<NB, 256, 0, stream>>>(subj, objp, L);
  score_pass1<<<NB*64, 256, 0, stream>>>(subj, objp, L, cnt, cand, ghist);
  pick_thresh<<<NB, 256, 0, stream>>>(ghist, cnt, T, flag);
  score_repair<<<NB*64, 256, 0, stream>>>(subj, objp, T, flag, cnt2, cand);
  final_select<<<NB, 256, 0, stream>>>(cnt, cnt2, flag, cand, out);
}